// Round 6
// baseline (564.980 us; speedup 1.0000x reference)
//
#include <hip/hip_runtime.h>
#include <math.h>

#define NUM_E 8
#define NTOK  32768      // B*T = 8*4096
#define TSEQ  4096
#define DM    512
#define DF    2048
#define CAP   6144       // per-bucket capacity (avg 4096, binomial sigma ~60)
#define PHROWS 8704      // H rows per 2-bucket phase (avg 8192 + 6-sigma slack)

typedef unsigned short ushort_t;
typedef __attribute__((ext_vector_type(8))) short short8;
typedef __attribute__((ext_vector_type(4))) float floatx4;

__device__ __forceinline__ unsigned short f2bf(float f){
  union { float f; unsigned int u; } v; v.f = f;
  unsigned int u = v.u;
  unsigned int r = (u + 0x7FFFu + ((u >> 16) & 1u)) >> 16;  // RNE
  return (unsigned short)r;
}

// tanh-approx gelu, reduced: h * sigmoid(1.5957691h + 0.0713548163h^3)
__device__ __forceinline__ float gelu_fast(float h){
  float z = h * (1.5957691216057308f + 0.0713548162726009f * h * h);
  float e = __expf(-z);
  return h * __builtin_amdgcn_rcpf(1.0f + e);
}

__device__ __forceinline__ void gld_lds16(const void* g, void* l){
  __builtin_amdgcn_global_load_lds(
      (const __attribute__((address_space(1))) unsigned int*)g,
      (__attribute__((address_space(3))) unsigned int*)l, 16, 0, 0);
}

// ---------------------------------------------------------------------------
// k_setup: one dispatch doing routing + x->bf16 convert + both weight
// transposes (blocks partitioned by blockIdx.x). 1024 threads.
//   [0,32)          : hierarchical routing (LDS counts -> 8 global atomics)
//   [32,4128)       : x fp32 -> bf16 (one float4 per thread)
//   [4128,4640)     : W1 [E][DM][DF] -> w1t [E][DF][DM]  (4 64x64 tiles/block)
//   [4640,5152)     : W2 [E][DF][DM] -> w2t [E][DM][DF] with pi on the K rows
// pi: H columns (gemm2's K dim) are stored permuted within each 64-group:
// logical k sits at stored position pi(k)=(k%16)*4+k/16, so gemm1's epilogue
// stores are 8B-packed. Permuting BOTH H's cols and w2t's K-rows by the same
// pi leaves every dot product bit-identical.
// ---------------------------------------------------------------------------
__global__ __launch_bounds__(1024) void k_setup(
    const int* __restrict__ tok, float* __restrict__ ids_out,
    int* __restrict__ cnt, int* __restrict__ list,
    const float* __restrict__ x, ushort_t* __restrict__ xb,
    const float* __restrict__ W1, ushort_t* __restrict__ w1t,
    const float* __restrict__ W2, ushort_t* __restrict__ w2t)
{
  __shared__ int lcnt[NUM_E];
  __shared__ int lbase[NUM_E];
  __shared__ ushort_t s[4][64][65];
  int b = blockIdx.x;
  int tid = threadIdx.x;

  if (b < 32){                                         // ---- routing
    if (tid < NUM_E) lcnt[tid] = 0;
    __syncthreads();
    int flat = b * 1024 + tid;                         // 0..NTOK-1
    int bb = flat >> 12;                               // T = 4096
    int t = tok[flat];
    int base = bb * TSEQ + t;                          // b*T + token
    int e0 = base & 7;
    int e1 = (base + 1) & 7;
    ids_out[2*flat]   = (float)e0;
    ids_out[2*flat+1] = (float)e1;
    int lpos = atomicAdd(&lcnt[e0], 1);
    __syncthreads();
    if (tid < NUM_E) lbase[tid] = atomicAdd(&cnt[tid], lcnt[tid]);
    __syncthreads();
    int pos = lbase[e0] + lpos;
    if (pos < CAP) list[e0*CAP + pos] = flat;
    return;
  }
  if (b < 32 + 4096){                                  // ---- convert x
    int i = (b - 32)*1024 + tid;
    float4 v = ((const float4*)x)[i];
    ushort4 o;
    o.x = f2bf(v.x); o.y = f2bf(v.y); o.z = f2bf(v.z); o.w = f2bf(v.w);
    ((ushort4*)xb)[i] = o;
    return;
  }
  // ---- transposes: 4 subtiles per block
  int sub = tid >> 8, t8 = tid & 255;
  int tx = t8 & 63, ty = t8 >> 6;
  const float* in; ushort_t* out; int R, C, c0t, r0, perm;
  if (b < 32 + 4096 + 512){                            // W1
    int tile = (b - (32 + 4096))*4 + sub;
    int e = tile >> 8, rem = tile & 255;
    R = DM; C = DF;
    in  = W1 + (size_t)e * R * C;
    out = w1t + (size_t)e * R * C;
    c0t = (rem & 31) * 64; r0 = (rem >> 5) * 64; perm = 0;
  } else {                                             // W2 (with pi)
    int tile = (b - (32 + 4096 + 512))*4 + sub;
    int e = tile >> 8, rem = tile & 255;
    R = DF; C = DM;
    in  = W2 + (size_t)e * R * C;
    out = w2t + (size_t)e * R * C;
    c0t = (rem & 7) * 64; r0 = (rem >> 3) * 64; perm = 1;
  }
  for (int rr = ty; rr < 64; rr += 4)
    s[sub][rr][tx] = f2bf(in[(size_t)(r0+rr)*C + c0t + tx]);
  __syncthreads();
  // stored position r0+tx holds logical row r0 + pi^{-1}(tx); pi^{-1}(p)=(p%4)*16+p/4
  int sx = perm ? ((tx & 3)*16 + (tx >> 2)) : tx;
  for (int ccx = ty; ccx < 64; ccx += 4)
    out[(size_t)(c0t+ccx)*R + r0 + tx] = s[sub][sx][ccx];
}

__global__ void k_finalize(const int* __restrict__ cnt, int* __restrict__ off,
                           float* __restrict__ counts_out){
  int tid = threadIdx.x;
  if (tid == 0){
    int s = 0;
    for (int c = 0; c < NUM_E; c++){ off[c] = s; s += cnt[c]; }
    off[NUM_E] = s;                                    // total sentinel
  }
  if (tid < NUM_E)
    counts_out[tid] = (float)(cnt[tid] + cnt[(tid + 7) & 7]); // slot0(bucket e) + slot1(bucket e-1)
}

// LDS tile layout (both GEMM bodies): 128 rows x 64 ushort, row-major; within
// each row the eight 16B chunks are XOR-swizzled: chunk c of row r sits at
// slot c^(r&7). Staging lane L fetches global chunk (L&7)^(L>>3); fragment
// reads use ((quad+4*ks)^(col&7)) — conflict-free (proven, 0 conflicts).

// GEMM1 body (round-5 verbatim, 128x128 tile, pi-packed epilogue):
//   H[(off[c]-off[c0])+i][slot*DF + pi-layout(n)] = gelu(x[list[c][i]] @ W1[e] + b1[e])
__device__ __forceinline__ void gemm1_body(
    char* smem, const ushort_t* __restrict__ xb, const ushort_t* __restrict__ w1t,
    const float* __restrict__ b1, const int* __restrict__ cnt,
    const int* __restrict__ off, const int* __restrict__ list,
    ushort_t* __restrict__ H, int c0, int zz)
{
  ushort_t* As = (ushort_t*)smem;
  ushort_t* Bs = (ushort_t*)(smem + 16384);
  unsigned int* rowoff = (unsigned int*)(smem + 32768);

  int c = c0 + (zz >> 1), slot = zz & 1;
  int e = (c + slot) & 7;
  int n_c = cnt[c];
  int m0 = blockIdx.x * 128;
  if (m0 >= n_c) return;
  int n0 = blockIdx.y * 128;

  int tid = threadIdx.x;
  int lane = tid & 63, w = tid >> 6;

  if (tid < 128){
    int i = m0 + tid;
    int tk = list[c*CAP + ((i < n_c) ? i : 0)];
    rowoff[tid] = (unsigned int)tk * (DM*2);
  }
  __syncthreads();

  int rl = lane >> 3;                 // row within 8-row staging block
  int cc = (lane & 7) ^ rl;           // swizzled source chunk
  unsigned int aoff[4], boff[4];
  const char* w1te = (const char*)w1t + (size_t)e * ((size_t)DF*DM*2);
  #pragma unroll
  for (int j = 0; j < 4; j++){
    int r = j*32 + w*8 + rl;
    aoff[j] = rowoff[r] + (unsigned int)cc*16u;
    boff[j] = (unsigned int)(n0 + r) * (DM*2) + (unsigned int)cc*16u;
  }

  floatx4 acc[4][4];
  #pragma unroll
  for (int a = 0; a < 4; a++)
    #pragma unroll
    for (int q = 0; q < 4; q++) acc[a][q] = floatx4{0.f,0.f,0.f,0.f};

  int wr = w >> 1, wc = w & 1;
  int col = lane & 15, quad = lane >> 4;
  int xa = col & 7;
  const ushort_t* A0 = As + (wr*64 + col)*64 + (quad ^ xa)*8;        // ks=0
  const ushort_t* A1 = As + (wr*64 + col)*64 + ((quad + 4) ^ xa)*8;  // ks=1
  const ushort_t* B0 = Bs + (wc*64 + col)*64 + (quad ^ xa)*8;
  const ushort_t* B1 = Bs + (wc*64 + col)*64 + ((quad + 4) ^ xa)*8;
  char* AsW = (char*)As + w*1024;
  char* BsW = (char*)Bs + w*1024;

  for (int k0 = 0; k0 < DM; k0 += 64){
    #pragma unroll
    for (int j = 0; j < 4; j++){
      gld_lds16((const char*)xb + aoff[j] + k0*2, AsW + j*4096);
      gld_lds16(w1te + boff[j] + k0*2, BsW + j*4096);
    }
    __syncthreads();
    {
      short8 a[4], bfr[4];
      #pragma unroll
      for (int mi = 0; mi < 4; mi++) a[mi] = *(const short8*)(A0 + mi*1024);
      #pragma unroll
      for (int ni = 0; ni < 4; ni++) bfr[ni] = *(const short8*)(B0 + ni*1024);
      #pragma unroll
      for (int mi = 0; mi < 4; mi++)
        #pragma unroll
        for (int ni = 0; ni < 4; ni++)
          acc[mi][ni] = __builtin_amdgcn_mfma_f32_16x16x32_bf16(a[mi], bfr[ni], acc[mi][ni], 0, 0, 0);
      #pragma unroll
      for (int mi = 0; mi < 4; mi++) a[mi] = *(const short8*)(A1 + mi*1024);
      #pragma unroll
      for (int ni = 0; ni < 4; ni++) bfr[ni] = *(const short8*)(B1 + ni*1024);
      #pragma unroll
      for (int mi = 0; mi < 4; mi++)
        #pragma unroll
        for (int ni = 0; ni < 4; ni++)
          acc[mi][ni] = __builtin_amdgcn_mfma_f32_16x16x32_bf16(a[mi], bfr[ni], acc[mi][ni], 0, 0, 0);
    }
    __syncthreads();
  }

  // pi-packed epilogue: per (mi,r) one ushort4 store at stored pos col*4+{0..3}
  int hbase = off[c] - off[c0];
  const float* b1p = b1 + e*DF + n0 + wc*64;
  float bias[4];
  #pragma unroll
  for (int ni = 0; ni < 4; ni++) bias[ni] = b1p[ni*16 + col];
  ushort_t* hcol = H + (size_t)slot*DF + n0 + wc*64 + col*4;
  #pragma unroll
  for (int mi = 0; mi < 4; mi++){
    #pragma unroll
    for (int r = 0; r < 4; r++){
      int m = wr*64 + mi*16 + quad*4 + r;
      int i = m0 + m;
      if (i < n_c){
        ushort4 o;
        o.x = f2bf(gelu_fast(acc[mi][0][r] + bias[0]));
        o.y = f2bf(gelu_fast(acc[mi][1][r] + bias[1]));
        o.z = f2bf(gelu_fast(acc[mi][2][r] + bias[2]));
        o.w = f2bf(gelu_fast(acc[mi][3][r] + bias[3]));
        *(ushort4*)(hcol + (size_t)(hbase + i)*(2*DF)) = o;
      }
    }
  }
}

// GEMM2 body (round-0 verbatim; reads pi-laid-out H against pi-laid-out w2t):
//   out[list[c][i]][n] = 0.25*( H[..][0:4096] @ [W2[c];W2[c+1]] + b2[c]+b2[c+1] )
__device__ __forceinline__ void gemm2_body(
    char* smem, const ushort_t* __restrict__ H, const ushort_t* __restrict__ w2t,
    const float* __restrict__ b2, const int* __restrict__ cnt,
    const int* __restrict__ off, const int* __restrict__ list,
    float* __restrict__ out, int c0, int zz)
{
  ushort_t* As = (ushort_t*)smem;
  ushort_t* Bs = (ushort_t*)(smem + 16384);
  int* rowtok = (int*)(smem + 32768);

  int c = c0 + zz;
  int e1 = (c + 1) & 7;
  int n_c = cnt[c];
  int m0 = blockIdx.x * 128;
  if (m0 >= n_c) return;
  int n0 = blockIdx.y * 128;

  int tid = threadIdx.x;
  int lane = tid & 63, w = tid >> 6;
  int rowbase = off[c] - off[c0];
  int phaseTok = off[c0 + 2] - off[c0];               // nb = 2 phases

  if (tid < 128){
    int i = m0 + tid;
    rowtok[tid] = list[c*CAP + ((i < n_c) ? i : 0)];
  }

  int rl = lane >> 3;
  int cc = (lane & 7) ^ rl;
  unsigned int aoff[4], boff[4];
  #pragma unroll
  for (int j = 0; j < 4; j++){
    int r = j*32 + w*8 + rl;
    int rg = rowbase + m0 + r;
    if (rg > phaseTok - 1) rg = phaseTok - 1;           // stay inside phase H
    aoff[j] = (unsigned int)rg * (2*DF*2) + (unsigned int)cc*16u;
    boff[j] = (unsigned int)(n0 + r) * (DF*2) + (unsigned int)cc*16u;
  }
  const char* bb0 = (const char*)w2t + (size_t)c  * ((size_t)DM*DF*2);
  const char* bb1 = (const char*)w2t + (size_t)e1 * ((size_t)DM*DF*2);

  floatx4 acc[4][4];
  #pragma unroll
  for (int a = 0; a < 4; a++)
    #pragma unroll
    for (int q = 0; q < 4; q++) acc[a][q] = floatx4{0.f,0.f,0.f,0.f};

  int wr = w >> 1, wc = w & 1;
  int col = lane & 15, quad = lane >> 4;
  int xa = col & 7;
  const ushort_t* A0 = As + (wr*64 + col)*64 + (quad ^ xa)*8;
  const ushort_t* A1 = As + (wr*64 + col)*64 + ((quad + 4) ^ xa)*8;
  const ushort_t* B0 = Bs + (wc*64 + col)*64 + (quad ^ xa)*8;
  const ushort_t* B1 = Bs + (wc*64 + col)*64 + ((quad + 4) ^ xa)*8;
  char* AsW = (char*)As + w*1024;
  char* BsW = (char*)Bs + w*1024;

  for (int k0 = 0; k0 < 2*DF; k0 += 64){
    const char* bb = (k0 < DF) ? (bb0 + k0*2) : (bb1 + (k0 - DF)*2);
    #pragma unroll
    for (int j = 0; j < 4; j++){
      gld_lds16((const char*)H + aoff[j] + k0*2, AsW + j*4096);
      gld_lds16(bb + boff[j], BsW + j*4096);
    }
    __syncthreads();
    {
      short8 a[4], bfr[4];
      #pragma unroll
      for (int mi = 0; mi < 4; mi++) a[mi] = *(const short8*)(A0 + mi*1024);
      #pragma unroll
      for (int ni = 0; ni < 4; ni++) bfr[ni] = *(const short8*)(B0 + ni*1024);
      #pragma unroll
      for (int mi = 0; mi < 4; mi++)
        #pragma unroll
        for (int ni = 0; ni < 4; ni++)
          acc[mi][ni] = __builtin_amdgcn_mfma_f32_16x16x32_bf16(a[mi], bfr[ni], acc[mi][ni], 0, 0, 0);
      #pragma unroll
      for (int mi = 0; mi < 4; mi++) a[mi] = *(const short8*)(A1 + mi*1024);
      #pragma unroll
      for (int ni = 0; ni < 4; ni++) bfr[ni] = *(const short8*)(B1 + ni*1024);
      #pragma unroll
      for (int mi = 0; mi < 4; mi++)
        #pragma unroll
        for (int ni = 0; ni < 4; ni++)
          acc[mi][ni] = __builtin_amdgcn_mfma_f32_16x16x32_bf16(a[mi], bfr[ni], acc[mi][ni], 0, 0, 0);
    }
    __syncthreads();
  }

  const float* b2a = b2 + c*DM;
  const float* b2b = b2 + e1*DM;
  #pragma unroll
  for (int mi = 0; mi < 4; mi++){
    #pragma unroll
    for (int r = 0; r < 4; r++){
      int m = wr*64 + mi*16 + quad*4 + r;
      int i = m0 + m;
      if (i < n_c){
        int tk = rowtok[m];
        float* orow = out + (size_t)tk*DM + n0 + wc*64;
        #pragma unroll
        for (int ni = 0; ni < 4; ni++){
          int nl = ni*16 + col;
          int gn = n0 + wc*64 + nl;
          orow[nl] = 0.25f * (acc[mi][ni][r] + b2a[gn] + b2b[gn]);
        }
      }
    }
  }
}

// ---------------------------------------------------------------------------
// Role-mux pipeline stage: one dispatch = gemm2(phase p-1) blocks (z < g2z,
// dispatched first: long K=4096 blocks) + gemm1(phase p) blocks (z >= g2z).
// gemm1(p) is independent of gemm2(p-1); H double-buffered by phase parity.
// Fixes gemm2's chronic underfill (512 blocks = 2/CU alone) by packing it
// with gemm1's 2112 blocks in the same dispatch.
// ---------------------------------------------------------------------------
__global__ __launch_bounds__(256, 4) void k_fused(
    const ushort_t* __restrict__ xb, const ushort_t* __restrict__ w1t,
    const float* __restrict__ b1,
    const ushort_t* __restrict__ w2t, const float* __restrict__ b2,
    const int* __restrict__ cnt, const int* __restrict__ off,
    const int* __restrict__ list,
    ushort_t* __restrict__ H0, ushort_t* __restrict__ H1,
    float* __restrict__ out, int p, int g2z)
{
  __shared__ char smem[33280];                 // As 16K | Bs 16K | row meta 512B
  int zz = blockIdx.z;
  if (zz < g2z){
    if (blockIdx.y >= DM/128) return;          // gemm2 only needs 4 column tiles
    const ushort_t* Hr = ((p - 1) & 1) ? H1 : H0;
    gemm2_body(smem, Hr, w2t, b2, cnt, off, list, out, 2*(p-1), zz);
  } else {
    ushort_t* Hw = (p & 1) ? H1 : H0;
    gemm1_body(smem, xb, w1t, b1, cnt, off, list, Hw, 2*p, zz - g2z);
  }
}

extern "C" void kernel_launch(void* const* d_in, const int* in_sizes, int n_in,
                              void* d_out, int out_size, void* d_ws, size_t ws_size,
                              hipStream_t stream){
  const float* x   = (const float*)d_in[0];
  const int*   tok = (const int*)d_in[1];
  const float* W1  = (const float*)d_in[2];
  const float* b1  = (const float*)d_in[3];
  const float* W2  = (const float*)d_in[4];
  const float* b2  = (const float*)d_in[5];

  float* out        = (float*)d_out;                       // (B,T,D) f32
  float* ids_out    = out + (size_t)NTOK*DM;               // (B,T,2) as f32
  float* counts_out = ids_out + (size_t)NTOK*2;            // (E,)    as f32

  char* ws = (char*)d_ws;
  int* cnt  = (int*)ws;                                    // 16 ints
  int* off  = cnt + 16;                                    // 9 (incl. total)
  int* list = (int*)(ws + 4096);                           // 8*CAP ints (192 KB)
  ushort_t* w1t = (ushort_t*)(ws + (1 << 20));             // [E][DF][DM] bf16 (16 MB)
  ushort_t* w2t = w1t + (size_t)NUM_E*DF*DM;               // [E][DM][DF] bf16 (16 MB)
  ushort_t* xb  = w2t + (size_t)NUM_E*DM*DF;               // [NTOK][DM]  bf16 (32 MB)
  ushort_t* H0  = (ushort_t*)(ws + (65ull << 20));         // phase H, parity 0

  // double-buffered H: 2 x PHROWS x (2*DF) bf16 = 142.6 MB — identical to the
  // proven nb=4 H footprint, so it fits the workspace.
  size_t fixed_b = 65ull << 20;
  size_t avail = (ws_size > fixed_b) ? (ws_size - fixed_b) : 0;
  size_t phbytes = (size_t)PHROWS * (2*DF) * sizeof(ushort_t);
  int overlap = (avail >= 2*phbytes) ? 1 : 0;
  ushort_t* H1 = overlap ? (H0 + (size_t)PHROWS * (2*DF)) : H0;

  hipMemsetAsync(cnt, 0, 64, stream);
  k_setup<<<32 + 4096 + 512 + 512, 1024, 0, stream>>>(
      tok, ids_out, cnt, list, x, xb, W1, w1t, W2, w2t);
  k_finalize<<<1, 64, 0, stream>>>(cnt, off, counts_out);

  if (overlap){
    // software pipeline over 5 stages: stage p = g2(p-1) + g1(p)
    for (int p = 0; p <= 4; p++){
      int g2z = (p > 0) ? 2 : 0;
      int g1z = (p < 4) ? 4 : 0;
      k_fused<<<dim3(CAP/128, DF/128, g2z + g1z), 256, 0, stream>>>(
          xb, w1t, b1, w2t, b2, cnt, off, list, H0, H1, out, p, g2z);
    }
  } else {
    // fallback: sequential per-phase (single H buffer)
    for (int p = 0; p < 4; p++){
      k_fused<<<dim3(CAP/128, DF/128, 4), 256, 0, stream>>>(
          xb, w1t, b1, w2t, b2, cnt, off, list, H0, H1, out, p, 0);
      k_fused<<<dim3(CAP/128, DM/128, 2), 256, 0, stream>>>(
          xb, w1t, b1, w2t, b2, cnt, off, list, H0, H1, out, p + 1, 2);
    }
  }
}

// Round 9
// 542.808 us; speedup vs baseline: 1.0408x; 1.0408x over previous
//
#include <hip/hip_runtime.h>
#include <math.h>

#define NUM_E 8
#define NTOK  32768      // B*T = 8*4096
#define TSEQ  4096
#define DM    512
#define DF    2048
#define CAP   6144       // per-bucket capacity (avg 4096, binomial sigma ~60)

typedef unsigned short ushort_t;
typedef __attribute__((ext_vector_type(8))) short short8;
typedef __attribute__((ext_vector_type(4))) float floatx4;

__device__ __forceinline__ unsigned short f2bf(float f){
  union { float f; unsigned int u; } v; v.f = f;
  unsigned int u = v.u;
  unsigned int r = (u + 0x7FFFu + ((u >> 16) & 1u)) >> 16;  // RNE
  return (unsigned short)r;
}

// tanh-approx gelu, reduced: h * sigmoid(1.5957691h + 0.0713548163h^3)
__device__ __forceinline__ float gelu_fast(float h){
  float z = h * (1.5957691216057308f + 0.0713548162726009f * h * h);
  float e = __expf(-z);
  return h * __builtin_amdgcn_rcpf(1.0f + e);
}

__device__ __forceinline__ void gld_lds16(const void* g, void* l){
  __builtin_amdgcn_global_load_lds(
      (const __attribute__((address_space(1))) unsigned int*)g,
      (__attribute__((address_space(3))) unsigned int*)l, 16, 0, 0);
}

// ---------------------------------------------------------------------------
// k_setup: one dispatch doing routing + x->bf16 convert + both weight
// transposes (blocks partitioned by blockIdx.x). 1024 threads. (validated r6)
//   [0,32)          : hierarchical routing (LDS counts -> 8 global atomics)
//   [32,4128)       : x fp32 -> bf16 (one float4 per thread)
//   [4128,4640)     : W1 [E][DM][DF] -> w1t [E][DF][DM]  (4 64x64 tiles/block)
//   [4640,5152)     : W2 [E][DF][DM] -> w2t [E][DM][DF] with pi on the K rows
// pi: H columns (gemm2's K dim) are stored permuted within each 64-group:
// logical k sits at stored position pi(k)=(k%16)*4+k/16, so gemm1's epilogue
// stores are 8B-packed. Permuting BOTH H's cols and w2t's K-rows by the same
// pi leaves every dot product bit-identical.
// ---------------------------------------------------------------------------
__global__ __launch_bounds__(1024) void k_setup(
    const int* __restrict__ tok, float* __restrict__ ids_out,
    int* __restrict__ cnt, int* __restrict__ list,
    const float* __restrict__ x, ushort_t* __restrict__ xb,
    const float* __restrict__ W1, ushort_t* __restrict__ w1t,
    const float* __restrict__ W2, ushort_t* __restrict__ w2t)
{
  __shared__ int lcnt[NUM_E];
  __shared__ int lbase[NUM_E];
  __shared__ ushort_t s[4][64][65];
  int b = blockIdx.x;
  int tid = threadIdx.x;

  if (b < 32){                                         // ---- routing
    if (tid < NUM_E) lcnt[tid] = 0;
    __syncthreads();
    int flat = b * 1024 + tid;                         // 0..NTOK-1
    int bb = flat >> 12;                               // T = 4096
    int t = tok[flat];
    int base = bb * TSEQ + t;                          // b*T + token
    int e0 = base & 7;
    int e1 = (base + 1) & 7;
    ids_out[2*flat]   = (float)e0;
    ids_out[2*flat+1] = (float)e1;
    int lpos = atomicAdd(&lcnt[e0], 1);
    __syncthreads();
    if (tid < NUM_E) lbase[tid] = atomicAdd(&cnt[tid], lcnt[tid]);
    __syncthreads();
    int pos = lbase[e0] + lpos;
    if (pos < CAP) list[e0*CAP + pos] = flat;
    return;
  }
  if (b < 32 + 4096){                                  // ---- convert x
    int i = (b - 32)*1024 + tid;
    float4 v = ((const float4*)x)[i];
    ushort4 o;
    o.x = f2bf(v.x); o.y = f2bf(v.y); o.z = f2bf(v.z); o.w = f2bf(v.w);
    ((ushort4*)xb)[i] = o;
    return;
  }
  // ---- transposes: 4 subtiles per block
  int sub = tid >> 8, t8 = tid & 255;
  int tx = t8 & 63, ty = t8 >> 6;
  const float* in; ushort_t* out; int R, C, c0t, r0, perm;
  if (b < 32 + 4096 + 512){                            // W1
    int tile = (b - (32 + 4096))*4 + sub;
    int e = tile >> 8, rem = tile & 255;
    R = DM; C = DF;
    in  = W1 + (size_t)e * R * C;
    out = w1t + (size_t)e * R * C;
    c0t = (rem & 31) * 64; r0 = (rem >> 5) * 64; perm = 0;
  } else {                                             // W2 (with pi)
    int tile = (b - (32 + 4096 + 512))*4 + sub;
    int e = tile >> 8, rem = tile & 255;
    R = DF; C = DM;
    in  = W2 + (size_t)e * R * C;
    out = w2t + (size_t)e * R * C;
    c0t = (rem & 7) * 64; r0 = (rem >> 3) * 64; perm = 1;
  }
  for (int rr = ty; rr < 64; rr += 4)
    s[sub][rr][tx] = f2bf(in[(size_t)(r0+rr)*C + c0t + tx]);
  __syncthreads();
  // stored position r0+tx holds logical row r0 + pi^{-1}(tx); pi^{-1}(p)=(p%4)*16+p/4
  int sx = perm ? ((tx & 3)*16 + (tx >> 2)) : tx;
  for (int ccx = ty; ccx < 64; ccx += 4)
    out[(size_t)(c0t+ccx)*R + r0 + tx] = s[sub][sx][ccx];
}

// (validated rounds 0-5)
__global__ void k_finalize(const int* __restrict__ cnt, int* __restrict__ off,
                           float* __restrict__ counts_out){
  int tid = threadIdx.x;
  if (tid == 0){
    int s = 0;
    for (int c = 0; c < NUM_E; c++){ off[c] = s; s += cnt[c]; }
    off[NUM_E] = s;                                    // total sentinel
  }
  if (tid < NUM_E)
    counts_out[tid] = (float)(cnt[tid] + cnt[(tid + 7) & 7]); // slot0(e) + slot1(e-1)
}

// LDS tile layout (both GEMMs): 128 rows x 64 ushort, row-major; within each
// row the eight 16B chunks are XOR-swizzled: chunk c of row r sits at slot
// c^(r&7). Staging lane L fetches global chunk (L&7)^(L>>3); fragment reads
// use ((quad+4*ks)^(col&7)) — conflict-free (proven, 0 conflicts all rounds).

// GEMM1 (round-5 champion, byte-identical: 128x128 tile, 4 blocks/CU,
// pi-packed epilogue; measured 103us / MfmaUtil 28.5):
//   H[(off[c]-off[c0])+i][slot*DF + pi-layout(n)] = gelu(x[list[c][i]] @ W1[e] + b1[e])
__global__ __launch_bounds__(256, 4) void k_gemm1(
    const ushort_t* __restrict__ xb, const ushort_t* __restrict__ w1t,
    const float* __restrict__ b1,
    const int* __restrict__ cnt, const int* __restrict__ off,
    const int* __restrict__ list, ushort_t* __restrict__ H, int c0)
{
  int c = c0 + (blockIdx.z >> 1), slot = blockIdx.z & 1;
  int e = (c + slot) & 7;
  int n_c = cnt[c];
  int m0 = blockIdx.x * 128;
  if (m0 >= n_c) return;
  int n0 = blockIdx.y * 128;

  __shared__ alignas(16) ushort_t As[128*64];
  __shared__ alignas(16) ushort_t Bs[128*64];
  __shared__ unsigned int rowoff[128];

  int tid = threadIdx.x;
  int lane = tid & 63, w = tid >> 6;

  if (tid < 128){
    int i = m0 + tid;
    int tk = list[c*CAP + ((i < n_c) ? i : 0)];
    rowoff[tid] = (unsigned int)tk * (DM*2);
  }
  __syncthreads();

  int rl = lane >> 3;                 // row within 8-row staging block
  int cc = (lane & 7) ^ rl;           // swizzled source chunk
  unsigned int aoff[4], boff[4];
  const char* w1te = (const char*)w1t + (size_t)e * ((size_t)DF*DM*2);
  #pragma unroll
  for (int j = 0; j < 4; j++){
    int r = j*32 + w*8 + rl;
    aoff[j] = rowoff[r] + (unsigned int)cc*16u;
    boff[j] = (unsigned int)(n0 + r) * (DM*2) + (unsigned int)cc*16u;
  }

  floatx4 acc[4][4];
  #pragma unroll
  for (int a = 0; a < 4; a++)
    #pragma unroll
    for (int q = 0; q < 4; q++) acc[a][q] = floatx4{0.f,0.f,0.f,0.f};

  int wr = w >> 1, wc = w & 1;
  int col = lane & 15, quad = lane >> 4;
  int xa = col & 7;
  const ushort_t* A0 = As + (wr*64 + col)*64 + (quad ^ xa)*8;        // ks=0
  const ushort_t* A1 = As + (wr*64 + col)*64 + ((quad + 4) ^ xa)*8;  // ks=1
  const ushort_t* B0 = Bs + (wc*64 + col)*64 + (quad ^ xa)*8;
  const ushort_t* B1 = Bs + (wc*64 + col)*64 + ((quad + 4) ^ xa)*8;
  char* AsW = (char*)As + w*1024;
  char* BsW = (char*)Bs + w*1024;

  for (int k0 = 0; k0 < DM; k0 += 64){
    #pragma unroll
    for (int j = 0; j < 4; j++){
      gld_lds16((const char*)xb + aoff[j] + k0*2, AsW + j*4096);
      gld_lds16(w1te + boff[j] + k0*2, BsW + j*4096);
    }
    __syncthreads();
    {
      short8 a[4], bfr[4];
      #pragma unroll
      for (int mi = 0; mi < 4; mi++) a[mi] = *(const short8*)(A0 + mi*1024);
      #pragma unroll
      for (int ni = 0; ni < 4; ni++) bfr[ni] = *(const short8*)(B0 + ni*1024);
      #pragma unroll
      for (int mi = 0; mi < 4; mi++)
        #pragma unroll
        for (int ni = 0; ni < 4; ni++)
          acc[mi][ni] = __builtin_amdgcn_mfma_f32_16x16x32_bf16(a[mi], bfr[ni], acc[mi][ni], 0, 0, 0);
      #pragma unroll
      for (int mi = 0; mi < 4; mi++) a[mi] = *(const short8*)(A1 + mi*1024);
      #pragma unroll
      for (int ni = 0; ni < 4; ni++) bfr[ni] = *(const short8*)(B1 + ni*1024);
      #pragma unroll
      for (int mi = 0; mi < 4; mi++)
        #pragma unroll
        for (int ni = 0; ni < 4; ni++)
          acc[mi][ni] = __builtin_amdgcn_mfma_f32_16x16x32_bf16(a[mi], bfr[ni], acc[mi][ni], 0, 0, 0);
    }
    __syncthreads();
  }

  // pi-packed epilogue: per (mi,r) one ushort4 store at stored pos col*4+{0..3}
  int hbase = off[c] - off[c0];
  const float* b1p = b1 + e*DF + n0 + wc*64;
  float bias[4];
  #pragma unroll
  for (int ni = 0; ni < 4; ni++) bias[ni] = b1p[ni*16 + col];
  ushort_t* hcol = H + (size_t)slot*DF + n0 + wc*64 + col*4;
  #pragma unroll
  for (int mi = 0; mi < 4; mi++){
    #pragma unroll
    for (int r = 0; r < 4; r++){
      int m = wr*64 + mi*16 + quad*4 + r;
      int i = m0 + m;
      if (i < n_c){
        ushort4 o;
        o.x = f2bf(gelu_fast(acc[mi][0][r] + bias[0]));
        o.y = f2bf(gelu_fast(acc[mi][1][r] + bias[1]));
        o.z = f2bf(gelu_fast(acc[mi][2][r] + bias[2]));
        o.w = f2bf(gelu_fast(acc[mi][3][r] + bias[3]));
        *(ushort4*)(hcol + (size_t)(hbase + i)*(2*DF)) = o;
      }
    }
  }
}

// GEMM2 (round-5 champion, byte-identical; reads pi-laid-out H against
// pi-laid-out w2t; measured ~95us):
//   out[list[c][i]][n] = 0.25*( H[..][0:4096] @ [W2[c];W2[c+1]] + b2[c]+b2[c+1] )
__global__ __launch_bounds__(256, 4) void k_gemm2(
    const ushort_t* __restrict__ H, const ushort_t* __restrict__ w2t,
    const float* __restrict__ b2,
    const int* __restrict__ cnt, const int* __restrict__ off,
    const int* __restrict__ list, float* __restrict__ out, int c0, int nb)
{
  int c = c0 + blockIdx.z;
  int e1 = (c + 1) & 7;
  int n_c = cnt[c];
  int m0 = blockIdx.x * 128;
  if (m0 >= n_c) return;
  int n0 = blockIdx.y * 128;

  __shared__ alignas(16) ushort_t As[128*64];
  __shared__ alignas(16) ushort_t Bs[128*64];
  __shared__ int rowtok[128];

  int tid = threadIdx.x;
  int lane = tid & 63, w = tid >> 6;
  int rowbase = off[c] - off[c0];
  int phaseTok = off[c0 + nb] - off[c0];

  if (tid < 128){
    int i = m0 + tid;
    rowtok[tid] = list[c*CAP + ((i < n_c) ? i : 0)];
  }

  int rl = lane >> 3;
  int cc = (lane & 7) ^ rl;
  unsigned int aoff[4], boff[4];
  #pragma unroll
  for (int j = 0; j < 4; j++){
    int r = j*32 + w*8 + rl;
    int rg = rowbase + m0 + r;
    if (rg > phaseTok - 1) rg = phaseTok - 1;           // stay inside phase H
    aoff[j] = (unsigned int)rg * (2*DF*2) + (unsigned int)cc*16u;
    boff[j] = (unsigned int)(n0 + r) * (DF*2) + (unsigned int)cc*16u;
  }
  const char* bb0 = (const char*)w2t + (size_t)c  * ((size_t)DM*DF*2);
  const char* bb1 = (const char*)w2t + (size_t)e1 * ((size_t)DM*DF*2);

  floatx4 acc[4][4];
  #pragma unroll
  for (int a = 0; a < 4; a++)
    #pragma unroll
    for (int q = 0; q < 4; q++) acc[a][q] = floatx4{0.f,0.f,0.f,0.f};

  int wr = w >> 1, wc = w & 1;
  int col = lane & 15, quad = lane >> 4;
  int xa = col & 7;
  const ushort_t* A0 = As + (wr*64 + col)*64 + (quad ^ xa)*8;
  const ushort_t* A1 = As + (wr*64 + col)*64 + ((quad + 4) ^ xa)*8;
  const ushort_t* B0 = Bs + (wc*64 + col)*64 + (quad ^ xa)*8;
  const ushort_t* B1 = Bs + (wc*64 + col)*64 + ((quad + 4) ^ xa)*8;
  char* AsW = (char*)As + w*1024;
  char* BsW = (char*)Bs + w*1024;

  for (int k0 = 0; k0 < 2*DF; k0 += 64){
    const char* bb = (k0 < DF) ? (bb0 + k0*2) : (bb1 + (k0 - DF)*2);
    #pragma unroll
    for (int j = 0; j < 4; j++){
      gld_lds16((const char*)H + aoff[j] + k0*2, AsW + j*4096);
      gld_lds16(bb + boff[j], BsW + j*4096);
    }
    __syncthreads();
    {
      short8 a[4], bfr[4];
      #pragma unroll
      for (int mi = 0; mi < 4; mi++) a[mi] = *(const short8*)(A0 + mi*1024);
      #pragma unroll
      for (int ni = 0; ni < 4; ni++) bfr[ni] = *(const short8*)(B0 + ni*1024);
      #pragma unroll
      for (int mi = 0; mi < 4; mi++)
        #pragma unroll
        for (int ni = 0; ni < 4; ni++)
          acc[mi][ni] = __builtin_amdgcn_mfma_f32_16x16x32_bf16(a[mi], bfr[ni], acc[mi][ni], 0, 0, 0);
      #pragma unroll
      for (int mi = 0; mi < 4; mi++) a[mi] = *(const short8*)(A1 + mi*1024);
      #pragma unroll
      for (int ni = 0; ni < 4; ni++) bfr[ni] = *(const short8*)(B1 + ni*1024);
      #pragma unroll
      for (int mi = 0; mi < 4; mi++)
        #pragma unroll
        for (int ni = 0; ni < 4; ni++)
          acc[mi][ni] = __builtin_amdgcn_mfma_f32_16x16x32_bf16(a[mi], bfr[ni], acc[mi][ni], 0, 0, 0);
    }
    __syncthreads();
  }

  const float* b2a = b2 + c*DM;
  const float* b2b = b2 + e1*DM;
  #pragma unroll
  for (int mi = 0; mi < 4; mi++){
    #pragma unroll
    for (int r = 0; r < 4; r++){
      int m = wr*64 + mi*16 + quad*4 + r;
      int i = m0 + m;
      if (i < n_c){
        int tk = rowtok[m];
        float* orow = out + (size_t)tk*DM + n0 + wc*64;
        #pragma unroll
        for (int ni = 0; ni < 4; ni++){
          int nl = ni*16 + col;
          int gn = n0 + wc*64 + nl;
          orow[nl] = 0.25f * (acc[mi][ni][r] + b2a[gn] + b2b[gn]);
        }
      }
    }
  }
}

extern "C" void kernel_launch(void* const* d_in, const int* in_sizes, int n_in,
                              void* d_out, int out_size, void* d_ws, size_t ws_size,
                              hipStream_t stream){
  const float* x   = (const float*)d_in[0];
  const int*   tok = (const int*)d_in[1];
  const float* W1  = (const float*)d_in[2];
  const float* b1  = (const float*)d_in[3];
  const float* W2  = (const float*)d_in[4];
  const float* b2  = (const float*)d_in[5];

  float* out        = (float*)d_out;                       // (B,T,D) f32
  float* ids_out    = out + (size_t)NTOK*DM;               // (B,T,2) as f32
  float* counts_out = ids_out + (size_t)NTOK*2;            // (E,)    as f32

  char* ws = (char*)d_ws;
  int* cnt  = (int*)ws;                                    // 16 ints
  int* off  = cnt + 16;                                    // 9 (incl. total)
  int* list = (int*)(ws + 4096);                           // 8*CAP ints (192 KB)
  ushort_t* w1t = (ushort_t*)(ws + (1 << 20));             // [E][DF][DM] bf16 (16 MB)
  ushort_t* w2t = w1t + (size_t)NUM_E*DF*DM;               // [E][DM][DF] bf16 (16 MB)
  ushort_t* xb  = w2t + (size_t)NUM_E*DM*DF;               // [NTOK][DM]  bf16 (32 MB)
  ushort_t* H   = (ushort_t*)(ws + (65ull << 20));         // phase H (bf16)

  // choose phase width nb so the H region fits in ws (validated rounds 0-5)
  size_t fixed_b = 65ull << 20;
  size_t avail = (ws_size > fixed_b) ? (ws_size - fixed_b) : 0;
  int nb = 0;
  for (int cand = 8; cand >= 1; cand >>= 1){
    size_t need = ((size_t)cand * 4096 + 1024) * (size_t)(2*DF) * 2;
    if (need <= avail){ nb = cand; break; }
  }
  if (nb == 0) nb = 1;   // last resort

  hipMemsetAsync(cnt, 0, 64, stream);
  k_setup<<<32 + 4096 + 512 + 512, 1024, 0, stream>>>(
      tok, ids_out, cnt, list, x, xb, W1, w1t, W2, w2t);
  k_finalize<<<1, 64, 0, stream>>>(cnt, off, counts_out);

  for (int c0 = 0; c0 < NUM_E; c0 += nb){
    k_gemm1<<<dim3(CAP/128, DF/128, 2*nb), 256, 0, stream>>>(
        xb, w1t, b1, cnt, off, list, H, c0);
    k_gemm2<<<dim3(CAP/128, DM/128, nb), 256, 0, stream>>>(
        H, w2t, b2, cnt, off, list, out, c0, nb);
  }
}